// Round 2
// baseline (313.074 us; speedup 1.0000x reference)
//
#include <hip/hip_runtime.h>

// Clifford Cl(3,0) geometric product. Streaming: 268 MB read + 134 MB write.
//
// R2 result: shuffle version, kernel 114 us @ 2.3 TB/s HBM, VALUBusy 17%,
// VGPR=20. Diagnosis: latency-bound, NOT bandwidth-bound. With 20 VGPRs the
// wave has only ~2 loads (2 KiB) in flight and fully drains vmcnt every
// iteration (shuffle depends on the load).
//
// R3 fix: unroll x4 with all 8 loads (va[4], vb[4] = 8 KiB/wave) issued
// back-to-back BEFORE any shuffle/compute -> 4x memory-level parallelism.
// Addresses stride by 256 inside a 1024-float4 block tile so every global
// load/store instruction remains lane-dense (64 lanes x 16 B contiguous).
// Lane-pair __shfl_xor(x,1) (DPP quad-perm, no LDS, no barrier) exchanges
// multivector halves as before.

__device__ __forceinline__ float4 clifford_half(float4 va, float4 vb, bool hi) {
    // Partner lane's halves.
    float4 pa, pb;
    pa.x = __shfl_xor(va.x, 1); pa.y = __shfl_xor(va.y, 1);
    pa.z = __shfl_xor(va.z, 1); pa.w = __shfl_xor(va.w, 1);
    pb.x = __shfl_xor(vb.x, 1); pb.y = __shfl_xor(vb.y, 1);
    pb.z = __shfl_xor(vb.z, 1); pb.w = __shfl_xor(vb.w, 1);

    float A0 = hi ? pa.x : va.x, A1 = hi ? pa.y : va.y;
    float A2 = hi ? pa.z : va.z, A3 = hi ? pa.w : va.w;
    float A4 = hi ? va.x : pa.x, A5 = hi ? va.y : pa.y;
    float A6 = hi ? va.z : pa.z, A7 = hi ? va.w : pa.w;
    float B0 = hi ? pb.x : vb.x, B1 = hi ? pb.y : vb.y;
    float B2 = hi ? pb.z : vb.z, B3 = hi ? pb.w : vb.w;
    float B4 = hi ? vb.x : pb.x, B5 = hi ? vb.y : pb.y;
    float B6 = hi ? vb.z : pb.z, B7 = hi ? vb.w : pb.w;

    float c0 = A0*B0 + A1*B1 + A2*B2 + A3*B3 - A4*B4 - A5*B5 - A6*B6 - A7*B7;
    float c1 = A0*B1 + A1*B0 - A2*B4 + A4*B2 - A3*B5 + A5*B3 - A6*B7 - A7*B6;
    float c2 = A0*B2 + A2*B0 + A1*B4 - A4*B1 - A3*B6 + A6*B3 + A5*B7 + A7*B5;
    float c3 = A0*B3 + A3*B0 + A1*B5 - A5*B1 + A2*B6 - A6*B2 - A4*B7 - A7*B4;
    float c4 = A0*B4 + A4*B0 + A1*B2 - A2*B1 - A5*B6 + A6*B5 + A3*B7 + A7*B3;
    float c5 = A0*B5 + A5*B0 + A1*B3 - A3*B1 + A4*B6 - A6*B4 - A2*B7 - A7*B2;
    float c6 = A0*B6 + A6*B0 + A2*B3 - A3*B2 - A4*B5 + A5*B4 + A1*B7 + A7*B1;
    float c7 = A0*B7 + A7*B0 + A1*B6 + A6*B1 - A2*B5 - A5*B2 + A3*B4 + A4*B3;

    return hi ? make_float4(c4, c5, c6, c7) : make_float4(c0, c1, c2, c3);
}

__global__ __launch_bounds__(256) void CliffordProduct_85452669321821_kernel(
    const float4* __restrict__ a, const float4* __restrict__ b,
    float4* __restrict__ out, int n4) {
    const bool hi = (threadIdx.x & 1);          // odd lane = high half (e4..e7)
    const int tileStride = gridDim.x * 1024;     // 4 x 256 float4 per block

    for (int base = blockIdx.x * 1024 + threadIdx.x; base < n4;
         base += tileStride) {
        if (base + 768 < n4) {
            // Fast path: all 8 loads issued before any use -> 8 KiB in
            // flight per wave.
            float4 va0 = a[base];       float4 va1 = a[base + 256];
            float4 va2 = a[base + 512]; float4 va3 = a[base + 768];
            float4 vb0 = b[base];       float4 vb1 = b[base + 256];
            float4 vb2 = b[base + 512]; float4 vb3 = b[base + 768];

            out[base]       = clifford_half(va0, vb0, hi);
            out[base + 256] = clifford_half(va1, vb1, hi);
            out[base + 512] = clifford_half(va2, vb2, hi);
            out[base + 768] = clifford_half(va3, vb3, hi);
        } else {
            // Tail: pairs (2k,2k+1) share the bounds check (n4 even, idx
            // parity matches lane parity), so shuffles stay pair-safe.
            #pragma unroll
            for (int u = 0; u < 4; ++u) {
                int idx = base + 256 * u;
                if (idx < n4) out[idx] = clifford_half(a[idx], b[idx], hi);
            }
        }
    }
}

extern "C" void kernel_launch(void* const* d_in, const int* in_sizes, int n_in,
                              void* d_out, int out_size, void* d_ws, size_t ws_size,
                              hipStream_t stream) {
    const float4* a = (const float4*)d_in[0];
    const float4* b = (const float4*)d_in[1];
    float4* out = (float4*)d_out;
    int n4 = in_sizes[0] / 4;  // total float4 elements (2 per multivector)

    int blocks = (n4 + 1023) / 1024;   // 1024 float4 per block-tile
    if (blocks > 2048) blocks = 2048;  // grid-stride beyond 8 blocks/CU
    CliffordProduct_85452669321821_kernel<<<blocks, 256, 0, stream>>>(a, b, out, n4);
}